// Round 6
// baseline (909.669 us; speedup 1.0000x reference)
//
#include <hip/hip_runtime.h>
#include <cstdint>
#include <cstddef>

#define S_LEN  2048
#define D_MODEL 1024
#define D_FF   2048
#define NLAYER 4
// H=8, DK=128, WINDOW=64 (half=32)

typedef float  f32x4  __attribute__((ext_vector_type(4)));
typedef __bf16 bf16x8 __attribute__((ext_vector_type(8)));

#define ATT_SCALE 0.08838834764831845f   // 1/sqrt(128)

__device__ __forceinline__ void async_copy16(const void* g, void* s) {
    __builtin_amdgcn_global_load_lds((const __attribute__((address_space(1))) void*)g,
                                     (__attribute__((address_space(3))) void*)s, 16, 0, 0);
}

template<int NW>
__device__ __forceinline__ float blockRedSum(float v, float* red) {
    #pragma unroll
    for (int off = 32; off > 0; off >>= 1) v += __shfl_down(v, off);
    const int t = threadIdx.x;
    if ((t & 63) == 0) red[t >> 6] = v;
    __syncthreads();
    float r = red[0];
    #pragma unroll
    for (int i = 1; i < NW; i++) r += red[i];
    __syncthreads();
    return r;
}

// blocks 0..2047: x = 2*enc + pe (fp32 + bf16). block 2048: mask setup + vmean zero.
__global__ __launch_bounds__(256)
void init_mask_kernel(const float* __restrict__ enc, float* __restrict__ x,
                      __bf16* __restrict__ xb, const int* __restrict__ gidx,
                      int* __restrict__ isg, int* __restrict__ gcols, int* __restrict__ ngc,
                      float* __restrict__ vmean) {
    const int t = threadIdx.x;
    if (blockIdx.x < S_LEN) {
        const int s = blockIdx.x;
        #pragma unroll
        for (int i = 0; i < 4; i++) {
            const int d = t + i * 256;
            const float freq = expf(-(float)(d & ~1) * (9.210340371976184f / 1024.0f));
            const float ang = (float)s * freq;
            const float pe = (d & 1) ? cosf(ang) : sinf(ang);
            const float v = 2.0f * enc[(size_t)s * D_MODEL + d] + pe;
            x[(size_t)s * D_MODEL + d] = v;
            xb[(size_t)s * D_MODEL + d] = (__bf16)v;
        }
    } else {
        #pragma unroll
        for (int i = 0; i < 4; i++) vmean[t + i * 256] = 0.0f;   // for layer-0 QKV VACC
        __shared__ int gsh[32];
        __shared__ int cnt;
        if (t < 32) {
            const int g = gidx[t] / 15;      // gidx >= 0
            gsh[t] = (g >= 0 && g < S_LEN) ? g : -1;
        }
        if (t == 0) cnt = 0;
        __syncthreads();
        #pragma unroll
        for (int i = 0; i < 8; i++) {
            const int s = t + i * 256;
            int f = 0;
            #pragma unroll
            for (int j = 0; j < 32; j++) f |= (gsh[j] == s) ? 1 : 0;
            isg[s] = f;
            if (f) { const int p = atomicAdd(&cnt, 1); gcols[p] = s; }
        }
        __syncthreads();
        if (t == 0) *ngc = cnt;
    }
}

// ALL 24 weight transposes (4 layers x 6 mats) in one dispatch.
// fp32 [K][N] -> bf16 [N][K]. Per-layer arena (8M elems):
//   WqT 0..1M, WkT 1M..2M, WvT 2M..3M, WoT 3M..4M, W1T 4M..6M, W2T 6M..8M
__global__ __launch_bounds__(256)
void transpose_all_kernel(const float* __restrict__ Wq, const float* __restrict__ Wk,
                          const float* __restrict__ Wv, const float* __restrict__ Wo,
                          const float* __restrict__ W1, const float* __restrict__ W2,
                          __bf16* __restrict__ out) {
    const int layer = blockIdx.x >> 13;
    int bid = blockIdx.x & 8191;
    const size_t lw = (size_t)layer * 1024 * 1024;
    const size_t lf = (size_t)layer * 1024 * 2048;
    __bf16* arena = out + (size_t)layer * 8 * 1024 * 1024;
    const float* in; __bf16* o; int K, N, r;
    if (bid < 4096) {
        const int m = bid >> 10; r = bid & 1023; K = 1024; N = 1024;
        in = ((m == 0) ? Wq : (m == 1) ? Wk : (m == 2) ? Wv : Wo) + lw;
        o  = arena + (size_t)m * 1024 * 1024;
    } else {
        bid -= 4096;
        const int m = bid >> 11; r = bid & 2047;
        if (m == 0) { in = W1 + lf; K = 1024; N = 2048; o = arena + (size_t)4 * 1024 * 1024; }
        else        { in = W2 + lf; K = 2048; N = 1024; o = arena + (size_t)6 * 1024 * 1024; }
    }
    const int ntx = N >> 5;
    const int n0 = (r % ntx) * 32, k0 = (r / ntx) * 32;
    __shared__ float tile[32][33];
    const int tx = threadIdx.x & 31, ty = threadIdx.x >> 5;
    #pragma unroll
    for (int i = ty; i < 32; i += 8)
        tile[i][tx] = in[(size_t)(k0 + i) * N + n0 + tx];
    __syncthreads();
    #pragma unroll
    for (int i = ty; i < 32; i += 8)
        o[(size_t)(n0 + i) * K + k0 + tx] = (__bf16)tile[tx][i];
}

// C[M][N] = A[M][K] * Bt[N][K]^T. BK-deep K-tiles (fewer barrier drains).
// EPI 0: fp32 out, 1: relu->bf16, 2: bf16.
// VACC: for cols >= 2048 (V block of fused QKV), atomicAdd fp32 column sums into vmean.
template<int BM, int BN, int BK, int EPI, bool VACC>
__global__ __launch_bounds__(256)
void gemm_bt(const __bf16* __restrict__ A, const __bf16* __restrict__ Bt,
             void* __restrict__ Cv, float* __restrict__ vmean, int M, int N, int K) {
    constexpr int WM = BM / 2, WN = BN / 2;
    constexpr int MI = WM / 16, NI = WN / 16;
    constexpr int TPR = BK / 8;          // threads per staged row
    constexpr int RPR = 2048 / BK;       // rows per 256-thread round
    constexpr int RA = BM / RPR, RB = BN / RPR;
    __shared__ __bf16 As[BM * BK];
    __shared__ __bf16 Bs[BN * BK];
    const int t = threadIdx.x;
    const int w = t >> 6, l = t & 63;
    const int l15 = l & 15, q4 = l >> 4;
    const int wr = w >> 1, wc = w & 1;
    const int m0 = blockIdx.y * BM, n0 = blockIdx.x * BN;

    const int srow = t / TPR;
    const int kc8  = (t % TPR) * 8;
    const __bf16* ag = A  + (size_t)(m0 + srow) * K + kc8;
    const __bf16* bg = Bt + (size_t)(n0 + srow) * K + kc8;
    __bf16* asw = As + w * 512;      // wave-uniform LDS base (+lane*16B by HW)
    __bf16* bsw = Bs + w * 512;

    const int aoff = (wr * WM + l15) * BK + q4 * 8;
    const int boff = (wc * WN + l15) * BK + q4 * 8;

    f32x4 acc[MI][NI];
    #pragma unroll
    for (int i = 0; i < MI; i++)
        #pragma unroll
        for (int j = 0; j < NI; j++) acc[i][j] = (f32x4){0.f, 0.f, 0.f, 0.f};

    for (int k0 = 0; k0 < K; k0 += BK) {
        #pragma unroll
        for (int rr = 0; rr < RA; rr++)
            async_copy16(ag + (size_t)rr * RPR * K + k0, asw + rr * 2048);
        #pragma unroll
        for (int rr = 0; rr < RB; rr++)
            async_copy16(bg + (size_t)rr * RPR * K + k0, bsw + rr * 2048);
        __syncthreads();
        #pragma unroll
        for (int s = 0; s < BK; s += 32) {
            bf16x8 af[MI], bfr[NI];
            #pragma unroll
            for (int i = 0; i < MI; i++) af[i]  = *(const bf16x8*)(As + aoff + i * 16 * BK + s);
            #pragma unroll
            for (int j = 0; j < NI; j++) bfr[j] = *(const bf16x8*)(Bs + boff + j * 16 * BK + s);
            #pragma unroll
            for (int i = 0; i < MI; i++)
                #pragma unroll
                for (int j = 0; j < NI; j++)
                    acc[i][j] = __builtin_amdgcn_mfma_f32_16x16x32_bf16(af[i], bfr[j], acc[i][j], 0, 0, 0);
        }
        __syncthreads();
    }

    const int r0 = m0 + wr * WM + q4 * 4;
    const int c0 = n0 + wc * WN + l15;
    if constexpr (EPI == 0) {
        float* C = (float*)Cv;
        #pragma unroll
        for (int i = 0; i < MI; i++)
            #pragma unroll
            for (int j = 0; j < NI; j++)
                #pragma unroll
                for (int r = 0; r < 4; r++)
                    C[(size_t)(r0 + i * 16 + r) * N + c0 + j * 16] = acc[i][j][r];
    } else if constexpr (EPI == 1) {
        __bf16* C = (__bf16*)Cv;
        #pragma unroll
        for (int i = 0; i < MI; i++)
            #pragma unroll
            for (int j = 0; j < NI; j++)
                #pragma unroll
                for (int r = 0; r < 4; r++)
                    C[(size_t)(r0 + i * 16 + r) * N + c0 + j * 16] = (__bf16)fmaxf(acc[i][j][r], 0.0f);
    } else {
        __bf16* C = (__bf16*)Cv;
        #pragma unroll
        for (int i = 0; i < MI; i++)
            #pragma unroll
            for (int j = 0; j < NI; j++)
                #pragma unroll
                for (int r = 0; r < 4; r++)
                    C[(size_t)(r0 + i * 16 + r) * N + c0 + j * 16] = (__bf16)acc[i][j][r];
    }
    if constexpr (VACC) {
        #pragma unroll
        for (int j = 0; j < NI; j++) {
            const int col = c0 + j * 16;
            if (col >= 2048) {
                float s = 0.f;
                #pragma unroll
                for (int i = 0; i < MI; i++)
                    #pragma unroll
                    for (int r = 0; r < 4; r++) s += acc[i][j][r];
                s += __shfl_xor(s, 16);
                s += __shfl_xor(s, 32);
                if (q4 == 0) atomicAdd(&vmean[col - 2048], s);
            }
        }
    }
}

// ---------------- fused MFMA attention: local tiles + global partials ----------------
// grid (80, 8): blockIdx.x < 64 -> local 32-row q-tile; else chunk cb = x-64 for global rows.
__global__ __launch_bounds__(256)
void attn_kernel(const __bf16* __restrict__ qkvb, const int* __restrict__ Tp,
                 const int* __restrict__ isg, const int* __restrict__ gcols,
                 const int* __restrict__ ngcp, const float* __restrict__ vmean,
                 __bf16* __restrict__ ctx, float* __restrict__ Og,
                 float* __restrict__ mg, float* __restrict__ lg) {
    const int h = blockIdx.y, hd = h * 128;
    const int t = threadIdx.x;
    const int T = *Tp, ng = *ngcp;
    __shared__ __bf16 Qs[32 * 136];
    __shared__ __bf16 Ks[128 * 136];
    __shared__ __bf16 Vs[128 * 136];
    __shared__ __bf16 Ps[32 * 136];
    __shared__ float  Ss[32 * 129];
    __shared__ int cix[128], cgf[128], rtype[32];
    __shared__ int ncs;
    const int l = t & 63, w = t >> 6;
    const int l15 = l & 15, q4 = l >> 4;
    const int nb = w * 32;

    if (blockIdx.x < 64) {
        // ================= local path =================
        const int qt0 = blockIdx.x * 32;
        const int wl = max(qt0 - 32, 0), wh = min(qt0 + 63, S_LEN - 1);
        if (t == 0) ncs = 0;
        if (t < 32) { const int qr = qt0 + t; rtype[t] = isg[qr] ? 1 : (qr < T ? 0 : 2); }
        __syncthreads();
        if (t <= wh - wl) {
            const int c = wl + t, gf = isg[c];
            if (c < T || gf) { const int p = atomicAdd(&ncs, 1); cix[p] = c; cgf[p] = gf; }
        }
        if (t < ng) {
            const int c = gcols[t];
            if (c < wl || c > wh) { const int p = atomicAdd(&ncs, 1); cix[p] = c; cgf[p] = 1; }
        }
        {
            const int r = t >> 3, d0 = (t & 7) * 16;
            const bf16x8* src = (const bf16x8*)(qkvb + (size_t)(qt0 + r) * 3072 + hd + d0);
            *(bf16x8*)&Qs[r * 136 + d0]     = src[0];
            *(bf16x8*)&Qs[r * 136 + d0 + 8] = src[1];
        }
        __syncthreads();
        const int nc = ncs;
        if (nc + t < 128) { cix[nc + t] = -1; cgf[nc + t] = 0; }
        {
            const int j = t >> 1, d0 = (t & 1) * 64;
            const int ci = (j < nc) ? cix[j] : -1;
            if (ci >= 0) {
                const bf16x8* kp = (const bf16x8*)(qkvb + (size_t)ci * 3072 + 1024 + hd + d0);
                const bf16x8* vp = (const bf16x8*)(qkvb + (size_t)ci * 3072 + 2048 + hd + d0);
                #pragma unroll
                for (int i = 0; i < 8; i++) {
                    *(bf16x8*)&Ks[j * 136 + d0 + i * 8] = kp[i];
                    *(bf16x8*)&Vs[j * 136 + d0 + i * 8] = vp[i];
                }
            } else {
                #pragma unroll
                for (int i = 0; i < 8; i++) {
                    *(bf16x8*)&Ks[j * 136 + d0 + i * 8] = (bf16x8)(__bf16)0.f;
                    *(bf16x8*)&Vs[j * 136 + d0 + i * 8] = (bf16x8)(__bf16)0.f;
                }
            }
        }
        __syncthreads();
        // S = Q K^T
        {
            f32x4 sacc[2][2];
            #pragma unroll
            for (int i = 0; i < 2; i++)
                #pragma unroll
                for (int j = 0; j < 2; j++) sacc[i][j] = (f32x4){0.f, 0.f, 0.f, 0.f};
            #pragma unroll
            for (int kk = 0; kk < 4; kk++) {
                const int k0 = kk * 32;
                bf16x8 af[2], bk[2];
                af[0] = *(const bf16x8*)&Qs[l15 * 136 + k0 + q4 * 8];
                af[1] = *(const bf16x8*)&Qs[(16 + l15) * 136 + k0 + q4 * 8];
                bk[0] = *(const bf16x8*)&Ks[(nb + l15) * 136 + k0 + q4 * 8];
                bk[1] = *(const bf16x8*)&Ks[(nb + 16 + l15) * 136 + k0 + q4 * 8];
                #pragma unroll
                for (int m2 = 0; m2 < 2; m2++)
                    #pragma unroll
                    for (int n2 = 0; n2 < 2; n2++)
                        sacc[m2][n2] = __builtin_amdgcn_mfma_f32_16x16x32_bf16(af[m2], bk[n2], sacc[m2][n2], 0, 0, 0);
            }
            #pragma unroll
            for (int m2 = 0; m2 < 2; m2++)
                #pragma unroll
                for (int n2 = 0; n2 < 2; n2++)
                    #pragma unroll
                    for (int r = 0; r < 4; r++) {
                        const int row = m2 * 16 + q4 * 4 + r;
                        const int col = nb + n2 * 16 + l15;
                        const int c = cix[col];
                        const int dd = qt0 + row - c;
                        const bool ok = (c >= 0) && (((unsigned)(dd + 32) <= 64u) || cgf[col]);
                        Ss[row * 129 + col] = ok ? sacc[m2][n2][r] * ATT_SCALE : -1e30f;
                    }
        }
        __syncthreads();
        // softmax (normalized) -> Ps bf16
        {
            const int r = t >> 3, i = t & 7;
            float mx = -1e30f;
            for (int c = i; c < 128; c += 8) mx = fmaxf(mx, Ss[r * 129 + c]);
            #pragma unroll
            for (int off = 4; off > 0; off >>= 1) mx = fmaxf(mx, __shfl_down(mx, off, 8));
            mx = __shfl(mx, 0, 8);
            float sm = 0.f;
            for (int c = i; c < 128; c += 8) {
                const float s = Ss[r * 129 + c];
                const float p = (s > -1e29f) ? __expf(s - mx) : 0.f;
                Ss[r * 129 + c] = p;
                sm += p;
            }
            #pragma unroll
            for (int off = 4; off > 0; off >>= 1) sm += __shfl_down(sm, off, 8);
            sm = __shfl(sm, 0, 8);
            const float rl = 1.0f / fmaxf(sm, 1e-30f);
            for (int c = i; c < 128; c += 8) Ps[r * 136 + c] = (__bf16)(Ss[r * 129 + c] * rl);
        }
        __syncthreads();
        // O = P V
        {
            f32x4 oacc[2][2];
            #pragma unroll
            for (int i = 0; i < 2; i++)
                #pragma unroll
                for (int j = 0; j < 2; j++) oacc[i][j] = (f32x4){0.f, 0.f, 0.f, 0.f};
            #pragma unroll
            for (int kk = 0; kk < 4; kk++) {
                const int k0 = kk * 32;
                bf16x8 ap[2], bv[2];
                ap[0] = *(const bf16x8*)&Ps[l15 * 136 + k0 + q4 * 8];
                ap[1] = *(const bf16x8*)&Ps[(16 + l15) * 136 + k0 + q4 * 8];
                #pragma unroll
                for (int n2 = 0; n2 < 2; n2++) {
                    const int dimn = nb + n2 * 16 + l15;
                    #pragma unroll
                    for (int jj = 0; jj < 8; jj++)
                        bv[n2][jj] = Vs[(k0 + q4 * 8 + jj) * 136 + dimn];
                }
                #pragma unroll
                for (int m2 = 0; m2 < 2; m2++)
                    #pragma unroll
                    for (int n2 = 0; n2 < 2; n2++)
                        oacc[m2][n2] = __builtin_amdgcn_mfma_f32_16x16x32_bf16(ap[m2], bv[n2], oacc[m2][n2], 0, 0, 0);
            }
            #pragma unroll
            for (int m2 = 0; m2 < 2; m2++)
                #pragma unroll
                for (int n2 = 0; n2 < 2; n2++)
                    #pragma unroll
                    for (int r = 0; r < 4; r++) {
                        const int row = m2 * 16 + q4 * 4 + r;
                        const int dim = nb + n2 * 16 + l15;
                        const int rt = rtype[row];
                        const size_t o = (size_t)(qt0 + row) * D_MODEL + hd + dim;
                        if (rt == 0)      ctx[o] = (__bf16)oacc[m2][n2][r];
                        else if (rt == 2) ctx[o] = (__bf16)(vmean[hd + dim] * (1.0f / 2048.0f));
                    }
        }
    } else {
        // ================= global partial path (chunk cb) =================
        if (ng == 0) return;
        const int cb = blockIdx.x - 64, c0 = cb * 128;
        {
            const int r = t >> 3, d0 = (t & 7) * 16;
            if (r < ng) {
                const bf16x8* src = (const bf16x8*)(qkvb + (size_t)gcols[r] * 3072 + hd + d0);
                *(bf16x8*)&Qs[r * 136 + d0]     = src[0];
                *(bf16x8*)&Qs[r * 136 + d0 + 8] = src[1];
            } else {
                *(bf16x8*)&Qs[r * 136 + d0]     = (bf16x8)(__bf16)0.f;
                *(bf16x8*)&Qs[r * 136 + d0 + 8] = (bf16x8)(__bf16)0.f;
            }
        }
        if (t < 128) { const int c = c0 + t; cix[t] = (c < T || isg[c]) ? 1 : 0; }  // validity flags
        {
            const int j = t >> 1, d0 = (t & 1) * 64;
            const int ci = c0 + j;
            const bf16x8* kp = (const bf16x8*)(qkvb + (size_t)ci * 3072 + 1024 + hd + d0);
            const bf16x8* vp = (const bf16x8*)(qkvb + (size_t)ci * 3072 + 2048 + hd + d0);
            #pragma unroll
            for (int i = 0; i < 8; i++) {
                *(bf16x8*)&Ks[j * 136 + d0 + i * 8] = kp[i];
                *(bf16x8*)&Vs[j * 136 + d0 + i * 8] = vp[i];
            }
        }
        __syncthreads();
        {
            f32x4 sacc[2][2];
            #pragma unroll
            for (int i = 0; i < 2; i++)
                #pragma unroll
                for (int j = 0; j < 2; j++) sacc[i][j] = (f32x4){0.f, 0.f, 0.f, 0.f};
            #pragma unroll
            for (int kk = 0; kk < 4; kk++) {
                const int k0 = kk * 32;
                bf16x8 af[2], bk[2];
                af[0] = *(const bf16x8*)&Qs[l15 * 136 + k0 + q4 * 8];
                af[1] = *(const bf16x8*)&Qs[(16 + l15) * 136 + k0 + q4 * 8];
                bk[0] = *(const bf16x8*)&Ks[(nb + l15) * 136 + k0 + q4 * 8];
                bk[1] = *(const bf16x8*)&Ks[(nb + 16 + l15) * 136 + k0 + q4 * 8];
                #pragma unroll
                for (int m2 = 0; m2 < 2; m2++)
                    #pragma unroll
                    for (int n2 = 0; n2 < 2; n2++)
                        sacc[m2][n2] = __builtin_amdgcn_mfma_f32_16x16x32_bf16(af[m2], bk[n2], sacc[m2][n2], 0, 0, 0);
            }
            #pragma unroll
            for (int m2 = 0; m2 < 2; m2++)
                #pragma unroll
                for (int n2 = 0; n2 < 2; n2++)
                    #pragma unroll
                    for (int r = 0; r < 4; r++) {
                        const int row = m2 * 16 + q4 * 4 + r;
                        const int col = nb + n2 * 16 + l15;
                        Ss[row * 129 + col] = cix[col] ? sacc[m2][n2][r] * ATT_SCALE : -1e30f;
                    }
        }
        __syncthreads();
        {
            const int r = t >> 3, i = t & 7;
            float mx = -1e30f;
            for (int c = i; c < 128; c += 8) mx = fmaxf(mx, Ss[r * 129 + c]);
            #pragma unroll
            for (int off = 4; off > 0; off >>= 1) mx = fmaxf(mx, __shfl_down(mx, off, 8));
            mx = __shfl(mx, 0, 8);
            float sm = 0.f;
            for (int c = i; c < 128; c += 8) {
                const float s = Ss[r * 129 + c];
                const float p = (s > -1e29f) ? __expf(s - mx) : 0.f;
                Ps[r * 136 + c] = (__bf16)p;
                sm += p;
            }
            #pragma unroll
            for (int off = 4; off > 0; off >>= 1) sm += __shfl_down(sm, off, 8);
            if (i == 0) { mg[(h * 16 + cb) * 32 + r] = mx; lg[(h * 16 + cb) * 32 + r] = sm; }
        }
        __syncthreads();
        {
            f32x4 oacc[2][2];
            #pragma unroll
            for (int i = 0; i < 2; i++)
                #pragma unroll
                for (int j = 0; j < 2; j++) oacc[i][j] = (f32x4){0.f, 0.f, 0.f, 0.f};
            #pragma unroll
            for (int kk = 0; kk < 4; kk++) {
                const int k0 = kk * 32;
                bf16x8 ap[2], bv[2];
                ap[0] = *(const bf16x8*)&Ps[l15 * 136 + k0 + q4 * 8];
                ap[1] = *(const bf16x8*)&Ps[(16 + l15) * 136 + k0 + q4 * 8];
                #pragma unroll
                for (int n2 = 0; n2 < 2; n2++) {
                    const int dimn = nb + n2 * 16 + l15;
                    #pragma unroll
                    for (int jj = 0; jj < 8; jj++)
                        bv[n2][jj] = Vs[(k0 + q4 * 8 + jj) * 136 + dimn];
                }
                #pragma unroll
                for (int m2 = 0; m2 < 2; m2++)
                    #pragma unroll
                    for (int n2 = 0; n2 < 2; n2++)
                        oacc[m2][n2] = __builtin_amdgcn_mfma_f32_16x16x32_bf16(ap[m2], bv[n2], oacc[m2][n2], 0, 0, 0);
            }
            #pragma unroll
            for (int m2 = 0; m2 < 2; m2++)
                #pragma unroll
                for (int n2 = 0; n2 < 2; n2++)
                    #pragma unroll
                    for (int r = 0; r < 4; r++) {
                        const int row = m2 * 16 + q4 * 4 + r;
                        const int dim = nb + n2 * 16 + l15;
                        Og[((size_t)(h * 16 + cb) * 32 + row) * 128 + dim] = oacc[m2][n2][r];
                    }
        }
    }
}

// combine the 16 chunks for global rows
__global__ __launch_bounds__(256)
void attn_gcomb(const int* __restrict__ gcols, const int* __restrict__ ngcp,
                const float* __restrict__ Og, const float* __restrict__ mg,
                const float* __restrict__ lg, __bf16* __restrict__ ctx) {
    const int h = blockIdx.x, hd = h * 128, t = threadIdx.x;
    const int ng = *ngcp;
    const int r = t >> 3, i = t & 7;
    if (r >= ng) return;
    float M = -1e30f;
    #pragma unroll
    for (int cb = 0; cb < 16; cb++) M = fmaxf(M, mg[(h * 16 + cb) * 32 + r]);
    float e[16], L = 0.f;
    #pragma unroll
    for (int cb = 0; cb < 16; cb++) {
        e[cb] = __expf(mg[(h * 16 + cb) * 32 + r] - M);
        L += e[cb] * lg[(h * 16 + cb) * 32 + r];
    }
    const float rL = 1.0f / fmaxf(L, 1e-30f);
    const int grow = gcols[r];
    for (int d = i; d < 128; d += 8) {
        float o = 0.f;
        #pragma unroll
        for (int cb = 0; cb < 16; cb++)
            o += e[cb] * Og[((size_t)(h * 16 + cb) * 32 + r) * 128 + d];
        ctx[(size_t)grow * D_MODEL + hd + d] = (__bf16)(o * rL);
    }
}

// x = LN(y + r); writes fp32 (xo) + bf16 (xb). vz: optional vmean zeroing (block 0).
__global__ __launch_bounds__(256)
void ln_kernel(const float* __restrict__ y, const float* __restrict__ r,
               const float* __restrict__ g, const float* __restrict__ b,
               float* __restrict__ xo, __bf16* __restrict__ xb, float* __restrict__ vz) {
    const int row = blockIdx.x, t = threadIdx.x;
    if (vz != nullptr && row == 0) {
        #pragma unroll
        for (int i = 0; i < 4; i++) vz[t + i * 256] = 0.0f;
    }
    const float* yr = y + (size_t)row * D_MODEL;
    const float* rr = r + (size_t)row * D_MODEL;
    __shared__ float red[4];
    float v[4]; float s = 0.f;
    #pragma unroll
    for (int i = 0; i < 4; i++) { const int d = t + i * 256; v[i] = yr[d] + rr[d]; s += v[i]; }
    s = blockRedSum<4>(s, red);
    const float mu = s * (1.0f / 1024.0f);
    float vs = 0.f;
    #pragma unroll
    for (int i = 0; i < 4; i++) { const float dd = v[i] - mu; vs += dd * dd; }
    vs = blockRedSum<4>(vs, red);
    const float rstd = rsqrtf(vs * (1.0f / 1024.0f) + 1e-5f);
    #pragma unroll
    for (int i = 0; i < 4; i++) {
        const int d = t + i * 256;
        const float o = g[d] * (v[i] - mu) * rstd + b[d];
        xo[(size_t)row * D_MODEL + d] = o;
        xb[(size_t)row * D_MODEL + d] = (__bf16)o;
    }
}

extern "C" void kernel_launch(void* const* d_in, const int* in_sizes, int n_in,
                              void* d_out, int out_size, void* d_ws, size_t ws_size,
                              hipStream_t stream) {
    const int*   Tp   = (const int*)  d_in[0];
    const float* enc  = (const float*)d_in[1];
    const int*   gidx = (const int*)  d_in[2];
    const float* Wq   = (const float*)d_in[3];
    const float* Wk   = (const float*)d_in[4];
    const float* Wv   = (const float*)d_in[5];
    const float* Wo   = (const float*)d_in[6];
    const float* ln1g = (const float*)d_in[7];
    const float* ln1b = (const float*)d_in[8];
    const float* W1   = (const float*)d_in[9];
    const float* W2   = (const float*)d_in[10];
    const float* ln2g = (const float*)d_in[11];
    const float* ln2b = (const float*)d_in[12];

    char* p = (char*)d_ws;
    size_t off = 0;
    auto alloc = [&](size_t bytes) -> void* {
        void* q = p + off;
        off += (bytes + 255) & ~(size_t)255;
        return q;
    };
    float*  x     = (float*) alloc((size_t)S_LEN * D_MODEL * 4);
    __bf16* xb    = (__bf16*)alloc((size_t)S_LEN * D_MODEL * 2);
    __bf16* qkvb  = (__bf16*)alloc((size_t)S_LEN * 3072 * 2);
    __bf16* ctx   = (__bf16*)alloc((size_t)S_LEN * D_MODEL * 2);
    float*  g1    = (float*) alloc((size_t)S_LEN * D_MODEL * 4);
    __bf16* h1    = (__bf16*)alloc((size_t)S_LEN * D_FF * 2);
    __bf16* wT    = (__bf16*)alloc((size_t)4 * 8 * 1024 * 1024 * 2);   // 4-layer arena (64 MB)
    float*  vmean = (float*) alloc(1024 * 4);
    int*    isg   = (int*)   alloc(S_LEN * 4);
    int*    gcols = (int*)   alloc(S_LEN * 4);
    int*    ngc   = (int*)   alloc(256);
    float*  Og    = (float*) alloc((size_t)8 * 16 * 32 * 128 * 4);
    float*  mgb   = (float*) alloc(8 * 16 * 32 * 4);
    float*  lgb   = (float*) alloc(8 * 16 * 32 * 4);

    init_mask_kernel<<<S_LEN + 1, 256, 0, stream>>>(enc, x, xb, gidx, isg, gcols, ngc, vmean);
    transpose_all_kernel<<<32768, 256, 0, stream>>>(Wq, Wk, Wv, Wo, W1, W2, wT);

    for (int l = 0; l < NLAYER; l++) {
        __bf16* wL = wT + (size_t)l * 8 * 1024 * 1024;
        // --- QKV projection (fused N=3072, bf16 out + fused vmean), BK=128 ---
        gemm_bt<64, 128, 128, 2, true><<<dim3(24, 32), 256, 0, stream>>>(xb, wL, (void*)qkvb, vmean, S_LEN, 3072, 1024);

        // --- attention: local tiles + global partials in one dispatch ---
        attn_kernel<<<dim3(80, 8), 256, 0, stream>>>(qkvb, Tp, isg, gcols, ngc, vmean, ctx, Og, mgb, lgb);
        attn_gcomb<<<8, 256, 0, stream>>>(gcols, ngc, Og, mgb, lgb, ctx);

        // --- output projection + LN1 ---
        gemm_bt<64, 64, 128, 0, false><<<dim3(16, 32), 256, 0, stream>>>(ctx, wL + (size_t)3 * 1024 * 1024, (void*)g1, nullptr, S_LEN, 1024, 1024);
        ln_kernel<<<S_LEN, 256, 0, stream>>>(g1, x, ln1g + l * 1024, ln1b + l * 1024, x, xb, nullptr);

        // --- FFN ---
        gemm_bt<64, 64, 128, 1, false><<<dim3(32, 32), 256, 0, stream>>>(xb, wL + (size_t)4 * 1024 * 1024, (void*)h1, nullptr, S_LEN, 2048, 1024);
        gemm_bt<64, 64, 128, 0, false><<<dim3(16, 32), 256, 0, stream>>>(h1, wL + (size_t)6 * 1024 * 1024, (void*)g1, nullptr, S_LEN, 1024, 2048);
        float* xout = (l == NLAYER - 1) ? (float*)d_out : x;
        ln_kernel<<<S_LEN, 256, 0, stream>>>(g1, x, ln2g + l * 1024, ln2b + l * 1024, xout, xb, vmean);
    }
}

// Round 7
// 683.404 us; speedup vs baseline: 1.3311x; 1.3311x over previous
//
#include <hip/hip_runtime.h>
#include <cstdint>
#include <cstddef>

#define S_LEN  2048
#define D_MODEL 1024
#define D_FF   2048
#define NLAYER 4
// H=8, DK=128, WINDOW=64 (half=32)

typedef float  f32x4  __attribute__((ext_vector_type(4)));
typedef __bf16 bf16x8 __attribute__((ext_vector_type(8)));
typedef __bf16 bf16x4 __attribute__((ext_vector_type(4)));

#define ATT_SCALE 0.08838834764831845f   // 1/sqrt(128)

__device__ __forceinline__ void async_copy16(const void* g, void* s) {
    __builtin_amdgcn_global_load_lds((const __attribute__((address_space(1))) void*)g,
                                     (__attribute__((address_space(3))) void*)s, 16, 0, 0);
}

template<int NW>
__device__ __forceinline__ float blockRedSum(float v, float* red) {
    #pragma unroll
    for (int off = 32; off > 0; off >>= 1) v += __shfl_down(v, off);
    const int t = threadIdx.x;
    if ((t & 63) == 0) red[t >> 6] = v;
    __syncthreads();
    float r = red[0];
    #pragma unroll
    for (int i = 1; i < NW; i++) r += red[i];
    __syncthreads();
    return r;
}

// blocks 0..2047: x = 2*enc + pe (fp32 + bf16). block 2048: mask setup + vmean zero.
__global__ __launch_bounds__(256)
void init_mask_kernel(const float* __restrict__ enc, float* __restrict__ x,
                      __bf16* __restrict__ xb, const int* __restrict__ gidx,
                      int* __restrict__ isg, int* __restrict__ gcols, int* __restrict__ ngc,
                      float* __restrict__ vmean) {
    const int t = threadIdx.x;
    if (blockIdx.x < S_LEN) {
        const int s = blockIdx.x;
        #pragma unroll
        for (int i = 0; i < 4; i++) {
            const int d = t + i * 256;
            const float freq = expf(-(float)(d & ~1) * (9.210340371976184f / 1024.0f));
            const float ang = (float)s * freq;
            const float pe = (d & 1) ? cosf(ang) : sinf(ang);
            const float v = 2.0f * enc[(size_t)s * D_MODEL + d] + pe;
            x[(size_t)s * D_MODEL + d] = v;
            xb[(size_t)s * D_MODEL + d] = (__bf16)v;
        }
    } else {
        #pragma unroll
        for (int i = 0; i < 4; i++) vmean[t + i * 256] = 0.0f;   // for layer-0 QKV VACC
        __shared__ int gsh[32];
        __shared__ int cnt;
        if (t < 32) {
            const int g = gidx[t] / 15;      // gidx >= 0
            gsh[t] = (g >= 0 && g < S_LEN) ? g : -1;
        }
        if (t == 0) cnt = 0;
        __syncthreads();
        #pragma unroll
        for (int i = 0; i < 8; i++) {
            const int s = t + i * 256;
            int f = 0;
            #pragma unroll
            for (int j = 0; j < 32; j++) f |= (gsh[j] == s) ? 1 : 0;
            isg[s] = f;
            if (f) { const int p = atomicAdd(&cnt, 1); gcols[p] = s; }
        }
        __syncthreads();
        if (t == 0) *ngc = cnt;
    }
}

// ALL 24 weight transposes (4 layers x 6 mats) in one dispatch.
// fp32 [K][N] -> bf16 [N][K]. Tiles: 128 K-rows x 32 N-cols -> output rows are
// 128 bf16 = 256 B contiguous writes. Per-layer arena (8M elems):
//   WqT 0..1M, WkT 1M..2M, WvT 2M..3M, WoT 3M..4M, W1T 4M..6M, W2T 6M..8M
__global__ __launch_bounds__(256)
void transpose_all_kernel(const float* __restrict__ Wq, const float* __restrict__ Wk,
                          const float* __restrict__ Wv, const float* __restrict__ Wo,
                          const float* __restrict__ W1, const float* __restrict__ W2,
                          __bf16* __restrict__ out) {
    const int layer = blockIdx.x >> 11;
    const int r = blockIdx.x & 2047;
    const size_t lw = (size_t)layer * 1024 * 1024;
    const size_t lf = (size_t)layer * 1024 * 2048;
    __bf16* arena = out + (size_t)layer * 8 * 1024 * 1024;
    const float* in; __bf16* o; int K, N, n0, k0;
    if (r < 1024) {               // Wq/Wk/Wv/Wo: 8 ktiles x 32 ntiles each
        const int m = r >> 8, rr = r & 255;
        in = ((m == 0) ? Wq : (m == 1) ? Wk : (m == 2) ? Wv : Wo) + lw;
        o  = arena + (size_t)m * 1024 * 1024;
        K = 1024; N = 1024; n0 = (rr & 31) * 32; k0 = (rr >> 5) * 128;
    } else if (r < 1536) {        // W1: 8 ktiles x 64 ntiles
        const int rr = r - 1024;
        in = W1 + lf; o = arena + (size_t)4 * 1024 * 1024;
        K = 1024; N = 2048; n0 = (rr & 63) * 32; k0 = (rr >> 6) * 128;
    } else {                      // W2: 16 ktiles x 32 ntiles
        const int rr = r - 1536;
        in = W2 + lf; o = arena + (size_t)6 * 1024 * 1024;
        K = 2048; N = 1024; n0 = (rr & 31) * 32; k0 = (rr >> 5) * 128;
    }
    __shared__ float tile[32][132];   // [n][k], 132 pad: fp32x4-aligned rows
    const int tx = threadIdx.x & 31, ty = threadIdx.x >> 5;
    #pragma unroll
    for (int i = ty; i < 128; i += 8)
        tile[tx][i] = in[(size_t)(k0 + i) * N + n0 + tx];
    __syncthreads();
    #pragma unroll
    for (int j = ty; j < 32; j += 8) {
        const float4 v = *(const float4*)&tile[j][tx * 4];
        bf16x4 b; b[0] = (__bf16)v.x; b[1] = (__bf16)v.y; b[2] = (__bf16)v.z; b[3] = (__bf16)v.w;
        *(bf16x4*)&o[(size_t)(n0 + j) * K + k0 + tx * 4] = b;
    }
}

// C[M][N] = A[M][K] * Bt[N][K]^T. BK=64, XOR-swizzled LDS (bank-conflict-free MFMA reads).
// EPI 0: fp32 out, 1: relu->bf16, 2: bf16.
// VACC: for cols >= 2048 (V block of fused QKV), atomicAdd fp32 column sums into vmean.
template<int BM, int BN, int EPI, bool VACC>
__global__ __launch_bounds__(256)
void gemm_bt(const __bf16* __restrict__ A, const __bf16* __restrict__ Bt,
             void* __restrict__ Cv, float* __restrict__ vmean, int M, int N, int K) {
    constexpr int WM = BM / 2, WN = BN / 2;
    constexpr int MI = WM / 16, NI = WN / 16;
    constexpr int RA = BM / 32, RB = BN / 32;      // 32 rows staged per 256-thread round
    __shared__ __bf16 As[BM * 64];
    __shared__ __bf16 Bs[BN * 64];
    const int t = threadIdx.x;
    const int w = t >> 6, l = t & 63;
    const int l15 = l & 15, q4 = l >> 4;
    const int wr = w >> 1, wc = w & 1;
    const int m0 = blockIdx.y * BM, n0 = blockIdx.x * BN;

    // staging: lane covers row srow, k-chunk (t&7)^(srow&7)  [XOR swizzle]
    const int srow = t >> 3;
    const int kc8  = (((t & 7) ^ (srow & 7)) * 8);
    const __bf16* ag = A  + (size_t)(m0 + srow) * K + kc8;
    const __bf16* bg = Bt + (size_t)(n0 + srow) * K + kc8;
    __bf16* asw = As + w * 512;      // wave-uniform LDS base (+lane*16B by HW)
    __bf16* bsw = Bs + w * 512;

    const int r7 = l15 & 7;
    int arow[MI], brow[NI];
    #pragma unroll
    for (int i = 0; i < MI; i++) arow[i] = (wr * WM + i * 16 + l15) * 64;
    #pragma unroll
    for (int j = 0; j < NI; j++) brow[j] = (wc * WN + j * 16 + l15) * 64;

    f32x4 acc[MI][NI];
    #pragma unroll
    for (int i = 0; i < MI; i++)
        #pragma unroll
        for (int j = 0; j < NI; j++) acc[i][j] = (f32x4){0.f, 0.f, 0.f, 0.f};

    for (int k0 = 0; k0 < K; k0 += 64) {
        #pragma unroll
        for (int rr = 0; rr < RA; rr++)
            async_copy16(ag + (size_t)rr * 32 * K + k0, asw + rr * 2048);
        #pragma unroll
        for (int rr = 0; rr < RB; rr++)
            async_copy16(bg + (size_t)rr * 32 * K + k0, bsw + rr * 2048);
        __syncthreads();
        #pragma unroll
        for (int s = 0; s < 64; s += 32) {
            const int slot = ((q4 + (s >> 3)) ^ r7) * 8;   // de-swizzle
            bf16x8 af[MI], bfr[NI];
            #pragma unroll
            for (int i = 0; i < MI; i++) af[i]  = *(const bf16x8*)(As + arow[i] + slot);
            #pragma unroll
            for (int j = 0; j < NI; j++) bfr[j] = *(const bf16x8*)(Bs + brow[j] + slot);
            #pragma unroll
            for (int i = 0; i < MI; i++)
                #pragma unroll
                for (int j = 0; j < NI; j++)
                    acc[i][j] = __builtin_amdgcn_mfma_f32_16x16x32_bf16(af[i], bfr[j], acc[i][j], 0, 0, 0);
        }
        __syncthreads();
    }

    const int r0 = m0 + wr * WM + q4 * 4;
    const int c0 = n0 + wc * WN + l15;
    if constexpr (EPI == 0) {
        float* C = (float*)Cv;
        #pragma unroll
        for (int i = 0; i < MI; i++)
            #pragma unroll
            for (int j = 0; j < NI; j++)
                #pragma unroll
                for (int r = 0; r < 4; r++)
                    C[(size_t)(r0 + i * 16 + r) * N + c0 + j * 16] = acc[i][j][r];
    } else if constexpr (EPI == 1) {
        __bf16* C = (__bf16*)Cv;
        #pragma unroll
        for (int i = 0; i < MI; i++)
            #pragma unroll
            for (int j = 0; j < NI; j++)
                #pragma unroll
                for (int r = 0; r < 4; r++)
                    C[(size_t)(r0 + i * 16 + r) * N + c0 + j * 16] = (__bf16)fmaxf(acc[i][j][r], 0.0f);
    } else {
        __bf16* C = (__bf16*)Cv;
        #pragma unroll
        for (int i = 0; i < MI; i++)
            #pragma unroll
            for (int j = 0; j < NI; j++)
                #pragma unroll
                for (int r = 0; r < 4; r++)
                    C[(size_t)(r0 + i * 16 + r) * N + c0 + j * 16] = (__bf16)acc[i][j][r];
    }
    if constexpr (VACC) {
        #pragma unroll
        for (int j = 0; j < NI; j++) {
            const int col = c0 + j * 16;
            if (col >= 2048) {
                float s = 0.f;
                #pragma unroll
                for (int i = 0; i < MI; i++)
                    #pragma unroll
                    for (int r = 0; r < 4; r++) s += acc[i][j][r];
                s += __shfl_xor(s, 16);
                s += __shfl_xor(s, 32);
                if (q4 == 0) atomicAdd(&vmean[col - 2048], s);
            }
        }
    }
}

// ---------------- fused MFMA attention: local tiles + global partials ----------------
// grid (80, 8): blockIdx.x < 64 -> local 32-row q-tile; else chunk cb = x-64 for global rows.
__global__ __launch_bounds__(256)
void attn_kernel(const __bf16* __restrict__ qkvb, const int* __restrict__ Tp,
                 const int* __restrict__ isg, const int* __restrict__ gcols,
                 const int* __restrict__ ngcp, const float* __restrict__ vmean,
                 __bf16* __restrict__ ctx, float* __restrict__ Og,
                 float* __restrict__ mg, float* __restrict__ lg) {
    const int h = blockIdx.y, hd = h * 128;
    const int t = threadIdx.x;
    const int T = *Tp, ng = *ngcp;
    __shared__ __bf16 Qs[32 * 136];
    __shared__ __bf16 Ks[128 * 136];
    __shared__ __bf16 Vs[128 * 136];
    __shared__ __bf16 Ps[32 * 136];
    __shared__ float  Ss[32 * 129];
    __shared__ int cix[128], cgf[128], rtype[32];
    __shared__ int ncs;
    const int l = t & 63, w = t >> 6;
    const int l15 = l & 15, q4 = l >> 4;
    const int nb = w * 32;

    if (blockIdx.x < 64) {
        // ================= local path =================
        const int qt0 = blockIdx.x * 32;
        const int wl = max(qt0 - 32, 0), wh = min(qt0 + 63, S_LEN - 1);
        if (t == 0) ncs = 0;
        if (t < 32) { const int qr = qt0 + t; rtype[t] = isg[qr] ? 1 : (qr < T ? 0 : 2); }
        __syncthreads();
        if (t <= wh - wl) {
            const int c = wl + t, gf = isg[c];
            if (c < T || gf) { const int p = atomicAdd(&ncs, 1); cix[p] = c; cgf[p] = gf; }
        }
        if (t < ng) {
            const int c = gcols[t];
            if (c < wl || c > wh) { const int p = atomicAdd(&ncs, 1); cix[p] = c; cgf[p] = 1; }
        }
        {
            const int r = t >> 3, d0 = (t & 7) * 16;
            const bf16x8* src = (const bf16x8*)(qkvb + (size_t)(qt0 + r) * 3072 + hd + d0);
            *(bf16x8*)&Qs[r * 136 + d0]     = src[0];
            *(bf16x8*)&Qs[r * 136 + d0 + 8] = src[1];
        }
        __syncthreads();
        const int nc = ncs;
        if (nc + t < 128) { cix[nc + t] = -1; cgf[nc + t] = 0; }
        {
            const int j = t >> 1, d0 = (t & 1) * 64;
            const int ci = (j < nc) ? cix[j] : -1;
            if (ci >= 0) {
                const bf16x8* kp = (const bf16x8*)(qkvb + (size_t)ci * 3072 + 1024 + hd + d0);
                const bf16x8* vp = (const bf16x8*)(qkvb + (size_t)ci * 3072 + 2048 + hd + d0);
                #pragma unroll
                for (int i = 0; i < 8; i++) {
                    *(bf16x8*)&Ks[j * 136 + d0 + i * 8] = kp[i];
                    *(bf16x8*)&Vs[j * 136 + d0 + i * 8] = vp[i];
                }
            } else {
                #pragma unroll
                for (int i = 0; i < 8; i++) {
                    *(bf16x8*)&Ks[j * 136 + d0 + i * 8] = (bf16x8)(__bf16)0.f;
                    *(bf16x8*)&Vs[j * 136 + d0 + i * 8] = (bf16x8)(__bf16)0.f;
                }
            }
        }
        __syncthreads();
        // S = Q K^T
        {
            f32x4 sacc[2][2];
            #pragma unroll
            for (int i = 0; i < 2; i++)
                #pragma unroll
                for (int j = 0; j < 2; j++) sacc[i][j] = (f32x4){0.f, 0.f, 0.f, 0.f};
            #pragma unroll
            for (int kk = 0; kk < 4; kk++) {
                const int k0 = kk * 32;
                bf16x8 af[2], bk[2];
                af[0] = *(const bf16x8*)&Qs[l15 * 136 + k0 + q4 * 8];
                af[1] = *(const bf16x8*)&Qs[(16 + l15) * 136 + k0 + q4 * 8];
                bk[0] = *(const bf16x8*)&Ks[(nb + l15) * 136 + k0 + q4 * 8];
                bk[1] = *(const bf16x8*)&Ks[(nb + 16 + l15) * 136 + k0 + q4 * 8];
                #pragma unroll
                for (int m2 = 0; m2 < 2; m2++)
                    #pragma unroll
                    for (int n2 = 0; n2 < 2; n2++)
                        sacc[m2][n2] = __builtin_amdgcn_mfma_f32_16x16x32_bf16(af[m2], bk[n2], sacc[m2][n2], 0, 0, 0);
            }
            #pragma unroll
            for (int m2 = 0; m2 < 2; m2++)
                #pragma unroll
                for (int n2 = 0; n2 < 2; n2++)
                    #pragma unroll
                    for (int r = 0; r < 4; r++) {
                        const int row = m2 * 16 + q4 * 4 + r;
                        const int col = nb + n2 * 16 + l15;
                        const int c = cix[col];
                        const int dd = qt0 + row - c;
                        const bool ok = (c >= 0) && (((unsigned)(dd + 32) <= 64u) || cgf[col]);
                        Ss[row * 129 + col] = ok ? sacc[m2][n2][r] * ATT_SCALE : -1e30f;
                    }
        }
        __syncthreads();
        // softmax (normalized) -> Ps bf16
        {
            const int r = t >> 3, i = t & 7;
            float mx = -1e30f;
            for (int c = i; c < 128; c += 8) mx = fmaxf(mx, Ss[r * 129 + c]);
            #pragma unroll
            for (int off = 4; off > 0; off >>= 1) mx = fmaxf(mx, __shfl_down(mx, off, 8));
            mx = __shfl(mx, 0, 8);
            float sm = 0.f;
            for (int c = i; c < 128; c += 8) {
                const float s = Ss[r * 129 + c];
                const float p = (s > -1e29f) ? __expf(s - mx) : 0.f;
                Ss[r * 129 + c] = p;
                sm += p;
            }
            #pragma unroll
            for (int off = 4; off > 0; off >>= 1) sm += __shfl_down(sm, off, 8);
            sm = __shfl(sm, 0, 8);
            const float rl = 1.0f / fmaxf(sm, 1e-30f);
            for (int c = i; c < 128; c += 8) Ps[r * 136 + c] = (__bf16)(Ss[r * 129 + c] * rl);
        }
        __syncthreads();
        // O = P V
        {
            f32x4 oacc[2][2];
            #pragma unroll
            for (int i = 0; i < 2; i++)
                #pragma unroll
                for (int j = 0; j < 2; j++) oacc[i][j] = (f32x4){0.f, 0.f, 0.f, 0.f};
            #pragma unroll
            for (int kk = 0; kk < 4; kk++) {
                const int k0 = kk * 32;
                bf16x8 ap[2], bv[2];
                ap[0] = *(const bf16x8*)&Ps[l15 * 136 + k0 + q4 * 8];
                ap[1] = *(const bf16x8*)&Ps[(16 + l15) * 136 + k0 + q4 * 8];
                #pragma unroll
                for (int n2 = 0; n2 < 2; n2++) {
                    const int dimn = nb + n2 * 16 + l15;
                    #pragma unroll
                    for (int jj = 0; jj < 8; jj++)
                        bv[n2][jj] = Vs[(k0 + q4 * 8 + jj) * 136 + dimn];
                }
                #pragma unroll
                for (int m2 = 0; m2 < 2; m2++)
                    #pragma unroll
                    for (int n2 = 0; n2 < 2; n2++)
                        oacc[m2][n2] = __builtin_amdgcn_mfma_f32_16x16x32_bf16(ap[m2], bv[n2], oacc[m2][n2], 0, 0, 0);
            }
            #pragma unroll
            for (int m2 = 0; m2 < 2; m2++)
                #pragma unroll
                for (int n2 = 0; n2 < 2; n2++)
                    #pragma unroll
                    for (int r = 0; r < 4; r++) {
                        const int row = m2 * 16 + q4 * 4 + r;
                        const int dim = nb + n2 * 16 + l15;
                        const int rt = rtype[row];
                        const size_t o = (size_t)(qt0 + row) * D_MODEL + hd + dim;
                        if (rt == 0)      ctx[o] = (__bf16)oacc[m2][n2][r];
                        else if (rt == 2) ctx[o] = (__bf16)(vmean[hd + dim] * (1.0f / 2048.0f));
                    }
        }
    } else {
        // ================= global partial path (chunk cb) =================
        if (ng == 0) return;
        const int cb = blockIdx.x - 64, c0 = cb * 128;
        {
            const int r = t >> 3, d0 = (t & 7) * 16;
            if (r < ng) {
                const bf16x8* src = (const bf16x8*)(qkvb + (size_t)gcols[r] * 3072 + hd + d0);
                *(bf16x8*)&Qs[r * 136 + d0]     = src[0];
                *(bf16x8*)&Qs[r * 136 + d0 + 8] = src[1];
            } else {
                *(bf16x8*)&Qs[r * 136 + d0]     = (bf16x8)(__bf16)0.f;
                *(bf16x8*)&Qs[r * 136 + d0 + 8] = (bf16x8)(__bf16)0.f;
            }
        }
        if (t < 128) { const int c = c0 + t; cix[t] = (c < T || isg[c]) ? 1 : 0; }  // validity flags
        {
            const int j = t >> 1, d0 = (t & 1) * 64;
            const int ci = c0 + j;
            const bf16x8* kp = (const bf16x8*)(qkvb + (size_t)ci * 3072 + 1024 + hd + d0);
            const bf16x8* vp = (const bf16x8*)(qkvb + (size_t)ci * 3072 + 2048 + hd + d0);
            #pragma unroll
            for (int i = 0; i < 8; i++) {
                *(bf16x8*)&Ks[j * 136 + d0 + i * 8] = kp[i];
                *(bf16x8*)&Vs[j * 136 + d0 + i * 8] = vp[i];
            }
        }
        __syncthreads();
        {
            f32x4 sacc[2][2];
            #pragma unroll
            for (int i = 0; i < 2; i++)
                #pragma unroll
                for (int j = 0; j < 2; j++) sacc[i][j] = (f32x4){0.f, 0.f, 0.f, 0.f};
            #pragma unroll
            for (int kk = 0; kk < 4; kk++) {
                const int k0 = kk * 32;
                bf16x8 af[2], bk[2];
                af[0] = *(const bf16x8*)&Qs[l15 * 136 + k0 + q4 * 8];
                af[1] = *(const bf16x8*)&Qs[(16 + l15) * 136 + k0 + q4 * 8];
                bk[0] = *(const bf16x8*)&Ks[(nb + l15) * 136 + k0 + q4 * 8];
                bk[1] = *(const bf16x8*)&Ks[(nb + 16 + l15) * 136 + k0 + q4 * 8];
                #pragma unroll
                for (int m2 = 0; m2 < 2; m2++)
                    #pragma unroll
                    for (int n2 = 0; n2 < 2; n2++)
                        sacc[m2][n2] = __builtin_amdgcn_mfma_f32_16x16x32_bf16(af[m2], bk[n2], sacc[m2][n2], 0, 0, 0);
            }
            #pragma unroll
            for (int m2 = 0; m2 < 2; m2++)
                #pragma unroll
                for (int n2 = 0; n2 < 2; n2++)
                    #pragma unroll
                    for (int r = 0; r < 4; r++) {
                        const int row = m2 * 16 + q4 * 4 + r;
                        const int col = nb + n2 * 16 + l15;
                        Ss[row * 129 + col] = cix[col] ? sacc[m2][n2][r] * ATT_SCALE : -1e30f;
                    }
        }
        __syncthreads();
        {
            const int r = t >> 3, i = t & 7;
            float mx = -1e30f;
            for (int c = i; c < 128; c += 8) mx = fmaxf(mx, Ss[r * 129 + c]);
            #pragma unroll
            for (int off = 4; off > 0; off >>= 1) mx = fmaxf(mx, __shfl_down(mx, off, 8));
            mx = __shfl(mx, 0, 8);
            float sm = 0.f;
            for (int c = i; c < 128; c += 8) {
                const float s = Ss[r * 129 + c];
                const float p = (s > -1e29f) ? __expf(s - mx) : 0.f;
                Ps[r * 136 + c] = (__bf16)p;
                sm += p;
            }
            #pragma unroll
            for (int off = 4; off > 0; off >>= 1) sm += __shfl_down(sm, off, 8);
            if (i == 0) { mg[(h * 16 + cb) * 32 + r] = mx; lg[(h * 16 + cb) * 32 + r] = sm; }
        }
        __syncthreads();
        {
            f32x4 oacc[2][2];
            #pragma unroll
            for (int i = 0; i < 2; i++)
                #pragma unroll
                for (int j = 0; j < 2; j++) oacc[i][j] = (f32x4){0.f, 0.f, 0.f, 0.f};
            #pragma unroll
            for (int kk = 0; kk < 4; kk++) {
                const int k0 = kk * 32;
                bf16x8 ap[2], bv[2];
                ap[0] = *(const bf16x8*)&Ps[l15 * 136 + k0 + q4 * 8];
                ap[1] = *(const bf16x8*)&Ps[(16 + l15) * 136 + k0 + q4 * 8];
                #pragma unroll
                for (int n2 = 0; n2 < 2; n2++) {
                    const int dimn = nb + n2 * 16 + l15;
                    #pragma unroll
                    for (int jj = 0; jj < 8; jj++)
                        bv[n2][jj] = Vs[(k0 + q4 * 8 + jj) * 136 + dimn];
                }
                #pragma unroll
                for (int m2 = 0; m2 < 2; m2++)
                    #pragma unroll
                    for (int n2 = 0; n2 < 2; n2++)
                        oacc[m2][n2] = __builtin_amdgcn_mfma_f32_16x16x32_bf16(ap[m2], bv[n2], oacc[m2][n2], 0, 0, 0);
            }
            #pragma unroll
            for (int m2 = 0; m2 < 2; m2++)
                #pragma unroll
                for (int n2 = 0; n2 < 2; n2++)
                    #pragma unroll
                    for (int r = 0; r < 4; r++) {
                        const int row = m2 * 16 + q4 * 4 + r;
                        const int dim = nb + n2 * 16 + l15;
                        Og[((size_t)(h * 16 + cb) * 32 + row) * 128 + dim] = oacc[m2][n2][r];
                    }
        }
    }
}

// combine the 16 chunks for global rows
__global__ __launch_bounds__(256)
void attn_gcomb(const int* __restrict__ gcols, const int* __restrict__ ngcp,
                const float* __restrict__ Og, const float* __restrict__ mg,
                const float* __restrict__ lg, __bf16* __restrict__ ctx) {
    const int h = blockIdx.x, hd = h * 128, t = threadIdx.x;
    const int ng = *ngcp;
    const int r = t >> 3, i = t & 7;
    if (r >= ng) return;
    float M = -1e30f;
    #pragma unroll
    for (int cb = 0; cb < 16; cb++) M = fmaxf(M, mg[(h * 16 + cb) * 32 + r]);
    float e[16], L = 0.f;
    #pragma unroll
    for (int cb = 0; cb < 16; cb++) {
        e[cb] = __expf(mg[(h * 16 + cb) * 32 + r] - M);
        L += e[cb] * lg[(h * 16 + cb) * 32 + r];
    }
    const float rL = 1.0f / fmaxf(L, 1e-30f);
    const int grow = gcols[r];
    for (int d = i; d < 128; d += 8) {
        float o = 0.f;
        #pragma unroll
        for (int cb = 0; cb < 16; cb++)
            o += e[cb] * Og[((size_t)(h * 16 + cb) * 32 + r) * 128 + d];
        ctx[(size_t)grow * D_MODEL + hd + d] = (__bf16)(o * rL);
    }
}

// x = LN(y + r); writes fp32 (xo) + bf16 (xb). vz: optional vmean zeroing (block 0).
__global__ __launch_bounds__(256)
void ln_kernel(const float* __restrict__ y, const float* __restrict__ r,
               const float* __restrict__ g, const float* __restrict__ b,
               float* __restrict__ xo, __bf16* __restrict__ xb, float* __restrict__ vz) {
    const int row = blockIdx.x, t = threadIdx.x;
    if (vz != nullptr && row == 0) {
        #pragma unroll
        for (int i = 0; i < 4; i++) vz[t + i * 256] = 0.0f;
    }
    const float* yr = y + (size_t)row * D_MODEL;
    const float* rr = r + (size_t)row * D_MODEL;
    __shared__ float red[4];
    float v[4]; float s = 0.f;
    #pragma unroll
    for (int i = 0; i < 4; i++) { const int d = t + i * 256; v[i] = yr[d] + rr[d]; s += v[i]; }
    s = blockRedSum<4>(s, red);
    const float mu = s * (1.0f / 1024.0f);
    float vs = 0.f;
    #pragma unroll
    for (int i = 0; i < 4; i++) { const float dd = v[i] - mu; vs += dd * dd; }
    vs = blockRedSum<4>(vs, red);
    const float rstd = rsqrtf(vs * (1.0f / 1024.0f) + 1e-5f);
    #pragma unroll
    for (int i = 0; i < 4; i++) {
        const int d = t + i * 256;
        const float o = g[d] * (v[i] - mu) * rstd + b[d];
        xo[(size_t)row * D_MODEL + d] = o;
        xb[(size_t)row * D_MODEL + d] = (__bf16)o;
    }
}

extern "C" void kernel_launch(void* const* d_in, const int* in_sizes, int n_in,
                              void* d_out, int out_size, void* d_ws, size_t ws_size,
                              hipStream_t stream) {
    const int*   Tp   = (const int*)  d_in[0];
    const float* enc  = (const float*)d_in[1];
    const int*   gidx = (const int*)  d_in[2];
    const float* Wq   = (const float*)d_in[3];
    const float* Wk   = (const float*)d_in[4];
    const float* Wv   = (const float*)d_in[5];
    const float* Wo   = (const float*)d_in[6];
    const float* ln1g = (const float*)d_in[7];
    const float* ln1b = (const float*)d_in[8];
    const float* W1   = (const float*)d_in[9];
    const float* W2   = (const float*)d_in[10];
    const float* ln2g = (const float*)d_in[11];
    const float* ln2b = (const float*)d_in[12];

    char* p = (char*)d_ws;
    size_t off = 0;
    auto alloc = [&](size_t bytes) -> void* {
        void* q = p + off;
        off += (bytes + 255) & ~(size_t)255;
        return q;
    };
    float*  x     = (float*) alloc((size_t)S_LEN * D_MODEL * 4);
    __bf16* xb    = (__bf16*)alloc((size_t)S_LEN * D_MODEL * 2);
    __bf16* qkvb  = (__bf16*)alloc((size_t)S_LEN * 3072 * 2);
    __bf16* ctx   = (__bf16*)alloc((size_t)S_LEN * D_MODEL * 2);
    float*  g1    = (float*) alloc((size_t)S_LEN * D_MODEL * 4);
    __bf16* h1    = (__bf16*)alloc((size_t)S_LEN * D_FF * 2);
    __bf16* wT    = (__bf16*)alloc((size_t)4 * 8 * 1024 * 1024 * 2);   // 4-layer arena (64 MB)
    float*  vmean = (float*) alloc(1024 * 4);
    int*    isg   = (int*)   alloc(S_LEN * 4);
    int*    gcols = (int*)   alloc(S_LEN * 4);
    int*    ngc   = (int*)   alloc(256);
    float*  Og    = (float*) alloc((size_t)8 * 16 * 32 * 128 * 4);
    float*  mgb   = (float*) alloc(8 * 16 * 32 * 4);
    float*  lgb   = (float*) alloc(8 * 16 * 32 * 4);

    init_mask_kernel<<<S_LEN + 1, 256, 0, stream>>>(enc, x, xb, gidx, isg, gcols, ngc, vmean);
    transpose_all_kernel<<<8192, 256, 0, stream>>>(Wq, Wk, Wv, Wo, W1, W2, wT);

    for (int l = 0; l < NLAYER; l++) {
        __bf16* wL = wT + (size_t)l * 8 * 1024 * 1024;
        // --- QKV projection (fused N=3072, bf16 out + fused vmean), BK=64 ---
        gemm_bt<64, 128, 2, true><<<dim3(24, 32), 256, 0, stream>>>(xb, wL, (void*)qkvb, vmean, S_LEN, 3072, 1024);

        // --- attention: local tiles + global partials in one dispatch ---
        attn_kernel<<<dim3(80, 8), 256, 0, stream>>>(qkvb, Tp, isg, gcols, ngc, vmean, ctx, Og, mgb, lgb);
        attn_gcomb<<<8, 256, 0, stream>>>(gcols, ngc, Og, mgb, lgb, ctx);

        // --- output projection + LN1 ---
        gemm_bt<64, 64, 0, false><<<dim3(16, 32), 256, 0, stream>>>(ctx, wL + (size_t)3 * 1024 * 1024, (void*)g1, nullptr, S_LEN, 1024, 1024);
        ln_kernel<<<S_LEN, 256, 0, stream>>>(g1, x, ln1g + l * 1024, ln1b + l * 1024, x, xb, nullptr);

        // --- FFN ---
        gemm_bt<64, 64, 1, false><<<dim3(32, 32), 256, 0, stream>>>(xb, wL + (size_t)4 * 1024 * 1024, (void*)h1, nullptr, S_LEN, 2048, 1024);
        gemm_bt<64, 64, 0, false><<<dim3(16, 32), 256, 0, stream>>>(h1, wL + (size_t)6 * 1024 * 1024, (void*)g1, nullptr, S_LEN, 1024, 2048);
        float* xout = (l == NLAYER - 1) ? (float*)d_out : x;
        ln_kernel<<<S_LEN, 256, 0, stream>>>(g1, x, ln2g + l * 1024, ln2b + l * 1024, xout, xb, vmean);
    }
}

// Round 8
// 682.765 us; speedup vs baseline: 1.3323x; 1.0009x over previous
//
#include <hip/hip_runtime.h>
#include <cstdint>
#include <cstddef>

#define S_LEN  2048
#define D_MODEL 1024
#define D_FF   2048
#define NLAYER 4
// H=8, DK=128, WINDOW=64 (half=32)

typedef float  f32x4  __attribute__((ext_vector_type(4)));
typedef __bf16 bf16x8 __attribute__((ext_vector_type(8)));
typedef __bf16 bf16x4 __attribute__((ext_vector_type(4)));

#define ATT_SCALE 0.08838834764831845f   // 1/sqrt(128)

__device__ __forceinline__ void async_copy16(const void* g, void* s) {
    __builtin_amdgcn_global_load_lds((const __attribute__((address_space(1))) void*)g,
                                     (__attribute__((address_space(3))) void*)s, 16, 0, 0);
}

template<int NW>
__device__ __forceinline__ float blockRedSum(float v, float* red) {
    #pragma unroll
    for (int off = 32; off > 0; off >>= 1) v += __shfl_down(v, off);
    const int t = threadIdx.x;
    if ((t & 63) == 0) red[t >> 6] = v;
    __syncthreads();
    float r = red[0];
    #pragma unroll
    for (int i = 1; i < NW; i++) r += red[i];
    __syncthreads();
    return r;
}

// blocks 0..2047: x = 2*enc + pe (fp32 + bf16). block 2048: mask setup + vmean zero.
__global__ __launch_bounds__(256)
void init_mask_kernel(const float* __restrict__ enc, float* __restrict__ x,
                      __bf16* __restrict__ xb, const int* __restrict__ gidx,
                      int* __restrict__ isg, int* __restrict__ gcols, int* __restrict__ ngc,
                      float* __restrict__ vmean) {
    const int t = threadIdx.x;
    if (blockIdx.x < S_LEN) {
        const int s = blockIdx.x;
        #pragma unroll
        for (int i = 0; i < 4; i++) {
            const int d = t + i * 256;
            const float freq = expf(-(float)(d & ~1) * (9.210340371976184f / 1024.0f));
            const float ang = (float)s * freq;
            const float pe = (d & 1) ? cosf(ang) : sinf(ang);
            const float v = 2.0f * enc[(size_t)s * D_MODEL + d] + pe;
            x[(size_t)s * D_MODEL + d] = v;
            xb[(size_t)s * D_MODEL + d] = (__bf16)v;
        }
    } else {
        #pragma unroll
        for (int i = 0; i < 4; i++) vmean[t + i * 256] = 0.0f;   // for layer-0 QKV VACC
        __shared__ int gsh[32];
        __shared__ int cnt;
        if (t < 32) {
            const int g = gidx[t] / 15;      // gidx >= 0
            gsh[t] = (g >= 0 && g < S_LEN) ? g : -1;
        }
        if (t == 0) cnt = 0;
        __syncthreads();
        #pragma unroll
        for (int i = 0; i < 8; i++) {
            const int s = t + i * 256;
            int f = 0;
            #pragma unroll
            for (int j = 0; j < 32; j++) f |= (gsh[j] == s) ? 1 : 0;
            isg[s] = f;
            if (f) { const int p = atomicAdd(&cnt, 1); gcols[p] = s; }
        }
        __syncthreads();
        if (t == 0) *ngc = cnt;
    }
}

// ALL 24 weight transposes (4 layers x 6 mats), 128K x 128N tiles, 2048 blocks.
// fp32 [K][N] -> bf16 [N][K]. bf16 LDS tile [n][k] with 148-elem row stride
// (74 words, 74%32=10 -> <=4-way write / 2-way read conflicts; 8B-aligned rows).
// Per-layer arena (8M elems): WqT 0..1M, WkT 1M..2M, WvT 2M..3M, WoT 3M..4M,
// W1T 4M..6M, W2T 6M..8M
__global__ __launch_bounds__(256)
void transpose_all_kernel(const float* __restrict__ Wq, const float* __restrict__ Wk,
                          const float* __restrict__ Wv, const float* __restrict__ Wo,
                          const float* __restrict__ W1, const float* __restrict__ W2,
                          __bf16* __restrict__ out) {
    const int layer = blockIdx.x >> 9;
    const int r = blockIdx.x & 511;
    const size_t lw = (size_t)layer * 1024 * 1024;
    const size_t lf = (size_t)layer * 1024 * 2048;
    __bf16* arena = out + (size_t)layer * 8 * 1024 * 1024;
    const float* in; __bf16* o; int K, N, n0, k0;
    if (r < 256) {                // Wq/Wk/Wv/Wo: 8 ktiles x 8 ntiles each
        const int m = r >> 6, rr = r & 63;
        in = ((m == 0) ? Wq : (m == 1) ? Wk : (m == 2) ? Wv : Wo) + lw;
        o  = arena + (size_t)m * 1024 * 1024;
        K = 1024; N = 1024; n0 = (rr & 7) * 128; k0 = (rr >> 3) * 128;
    } else if (r < 384) {         // W1: 8 ktiles x 16 ntiles
        const int rr = r - 256;
        in = W1 + lf; o = arena + (size_t)4 * 1024 * 1024;
        K = 1024; N = 2048; n0 = (rr & 15) * 128; k0 = (rr >> 4) * 128;
    } else {                      // W2: 16 ktiles x 8 ntiles
        const int rr = r - 384;
        in = W2 + lf; o = arena + (size_t)6 * 1024 * 1024;
        K = 2048; N = 1024; n0 = (rr & 7) * 128; k0 = (rr >> 3) * 128;
    }
    __shared__ __bf16 tile[128][148];     // [n][k], 37 KB
    const int t = threadIdx.x;
    {   // load: lane owns (n=tx, k-pair j2); global reads 256 B contiguous per wave
        const int tx = t & 127, tp = t >> 7;
        #pragma unroll
        for (int j2 = tp; j2 < 64; j2 += 2) {
            const float a = in[(size_t)(k0 + 2 * j2)     * N + n0 + tx];
            const float b = in[(size_t)(k0 + 2 * j2 + 1) * N + n0 + tx];
            __bf16 pr[2] = {(__bf16)a, (__bf16)b};
            *(uint32_t*)&tile[tx][2 * j2] = *(uint32_t*)pr;   // one aligned 4B word
        }
    }
    __syncthreads();
    {   // store: b64 LDS reads, 256 B contiguous bf16 global writes per row
        const int ktx = t & 31, j0 = t >> 5;
        #pragma unroll
        for (int j = j0; j < 128; j += 8) {
            const bf16x4 v = *(const bf16x4*)&tile[j][4 * ktx];
            *(bf16x4*)&o[(size_t)(n0 + j) * K + k0 + 4 * ktx] = v;
        }
    }
}

// C[M][N] = A[M][K] * Bt[N][K]^T. BK=64, XOR-swizzled LDS (bank-conflict-free MFMA reads).
// EPI 0: fp32 out, 1: relu->bf16, 2: bf16.
// VACC: for cols >= 2048 (V block of fused QKV), atomicAdd fp32 column sums into vmean.
template<int BM, int BN, int EPI, bool VACC>
__global__ __launch_bounds__(256)
void gemm_bt(const __bf16* __restrict__ A, const __bf16* __restrict__ Bt,
             void* __restrict__ Cv, float* __restrict__ vmean, int M, int N, int K) {
    constexpr int WM = BM / 2, WN = BN / 2;
    constexpr int MI = WM / 16, NI = WN / 16;
    constexpr int RA = BM / 32, RB = BN / 32;      // 32 rows staged per 256-thread round
    __shared__ __bf16 As[BM * 64];
    __shared__ __bf16 Bs[BN * 64];
    const int t = threadIdx.x;
    const int w = t >> 6, l = t & 63;
    const int l15 = l & 15, q4 = l >> 4;
    const int wr = w >> 1, wc = w & 1;
    const int m0 = blockIdx.y * BM, n0 = blockIdx.x * BN;

    // staging: lane covers row srow, k-chunk (t&7)^(srow&7)  [XOR swizzle]
    const int srow = t >> 3;
    const int kc8  = (((t & 7) ^ (srow & 7)) * 8);
    const __bf16* ag = A  + (size_t)(m0 + srow) * K + kc8;
    const __bf16* bg = Bt + (size_t)(n0 + srow) * K + kc8;
    __bf16* asw = As + w * 512;      // wave-uniform LDS base (+lane*16B by HW)
    __bf16* bsw = Bs + w * 512;

    const int r7 = l15 & 7;
    int arow[MI], brow[NI];
    #pragma unroll
    for (int i = 0; i < MI; i++) arow[i] = (wr * WM + i * 16 + l15) * 64;
    #pragma unroll
    for (int j = 0; j < NI; j++) brow[j] = (wc * WN + j * 16 + l15) * 64;

    f32x4 acc[MI][NI];
    #pragma unroll
    for (int i = 0; i < MI; i++)
        #pragma unroll
        for (int j = 0; j < NI; j++) acc[i][j] = (f32x4){0.f, 0.f, 0.f, 0.f};

    for (int k0 = 0; k0 < K; k0 += 64) {
        #pragma unroll
        for (int rr = 0; rr < RA; rr++)
            async_copy16(ag + (size_t)rr * 32 * K + k0, asw + rr * 2048);
        #pragma unroll
        for (int rr = 0; rr < RB; rr++)
            async_copy16(bg + (size_t)rr * 32 * K + k0, bsw + rr * 2048);
        __syncthreads();
        #pragma unroll
        for (int s = 0; s < 64; s += 32) {
            const int slot = ((q4 + (s >> 3)) ^ r7) * 8;   // de-swizzle
            bf16x8 af[MI], bfr[NI];
            #pragma unroll
            for (int i = 0; i < MI; i++) af[i]  = *(const bf16x8*)(As + arow[i] + slot);
            #pragma unroll
            for (int j = 0; j < NI; j++) bfr[j] = *(const bf16x8*)(Bs + brow[j] + slot);
            #pragma unroll
            for (int i = 0; i < MI; i++)
                #pragma unroll
                for (int j = 0; j < NI; j++)
                    acc[i][j] = __builtin_amdgcn_mfma_f32_16x16x32_bf16(af[i], bfr[j], acc[i][j], 0, 0, 0);
        }
        __syncthreads();
    }

    const int r0 = m0 + wr * WM + q4 * 4;
    const int c0 = n0 + wc * WN + l15;
    if constexpr (EPI == 0) {
        float* C = (float*)Cv;
        #pragma unroll
        for (int i = 0; i < MI; i++)
            #pragma unroll
            for (int j = 0; j < NI; j++)
                #pragma unroll
                for (int r = 0; r < 4; r++)
                    C[(size_t)(r0 + i * 16 + r) * N + c0 + j * 16] = acc[i][j][r];
    } else if constexpr (EPI == 1) {
        __bf16* C = (__bf16*)Cv;
        #pragma unroll
        for (int i = 0; i < MI; i++)
            #pragma unroll
            for (int j = 0; j < NI; j++)
                #pragma unroll
                for (int r = 0; r < 4; r++)
                    C[(size_t)(r0 + i * 16 + r) * N + c0 + j * 16] = (__bf16)fmaxf(acc[i][j][r], 0.0f);
    } else {
        __bf16* C = (__bf16*)Cv;
        #pragma unroll
        for (int i = 0; i < MI; i++)
            #pragma unroll
            for (int j = 0; j < NI; j++)
                #pragma unroll
                for (int r = 0; r < 4; r++)
                    C[(size_t)(r0 + i * 16 + r) * N + c0 + j * 16] = (__bf16)acc[i][j][r];
    }
    if constexpr (VACC) {
        #pragma unroll
        for (int j = 0; j < NI; j++) {
            const int col = c0 + j * 16;
            if (col >= 2048) {
                float s = 0.f;
                #pragma unroll
                for (int i = 0; i < MI; i++)
                    #pragma unroll
                    for (int r = 0; r < 4; r++) s += acc[i][j][r];
                s += __shfl_xor(s, 16);
                s += __shfl_xor(s, 32);
                if (q4 == 0) atomicAdd(&vmean[col - 2048], s);
            }
        }
    }
}

// ---------------- fused MFMA attention: local tiles + global partials ----------------
// grid (80, 8): blockIdx.x < 64 -> local 32-row q-tile; else chunk cb = x-64 for global rows.
__global__ __launch_bounds__(256)
void attn_kernel(const __bf16* __restrict__ qkvb, const int* __restrict__ Tp,
                 const int* __restrict__ isg, const int* __restrict__ gcols,
                 const int* __restrict__ ngcp, const float* __restrict__ vmean,
                 __bf16* __restrict__ ctx, float* __restrict__ Og,
                 float* __restrict__ mg, float* __restrict__ lg) {
    const int h = blockIdx.y, hd = h * 128;
    const int t = threadIdx.x;
    const int T = *Tp, ng = *ngcp;
    __shared__ __bf16 Qs[32 * 136];
    __shared__ __bf16 Ks[128 * 136];
    __shared__ __bf16 Vs[128 * 136];
    __shared__ __bf16 Ps[32 * 136];
    __shared__ float  Ss[32 * 129];
    __shared__ int cix[128], cgf[128], rtype[32];
    __shared__ int ncs;
    const int l = t & 63, w = t >> 6;
    const int l15 = l & 15, q4 = l >> 4;
    const int nb = w * 32;

    if (blockIdx.x < 64) {
        // ================= local path =================
        const int qt0 = blockIdx.x * 32;
        const int wl = max(qt0 - 32, 0), wh = min(qt0 + 63, S_LEN - 1);
        if (t == 0) ncs = 0;
        if (t < 32) { const int qr = qt0 + t; rtype[t] = isg[qr] ? 1 : (qr < T ? 0 : 2); }
        __syncthreads();
        if (t <= wh - wl) {
            const int c = wl + t, gf = isg[c];
            if (c < T || gf) { const int p = atomicAdd(&ncs, 1); cix[p] = c; cgf[p] = gf; }
        }
        if (t < ng) {
            const int c = gcols[t];
            if (c < wl || c > wh) { const int p = atomicAdd(&ncs, 1); cix[p] = c; cgf[p] = 1; }
        }
        {
            const int r = t >> 3, d0 = (t & 7) * 16;
            const bf16x8* src = (const bf16x8*)(qkvb + (size_t)(qt0 + r) * 3072 + hd + d0);
            *(bf16x8*)&Qs[r * 136 + d0]     = src[0];
            *(bf16x8*)&Qs[r * 136 + d0 + 8] = src[1];
        }
        __syncthreads();
        const int nc = ncs;
        if (nc + t < 128) { cix[nc + t] = -1; cgf[nc + t] = 0; }
        {
            const int j = t >> 1, d0 = (t & 1) * 64;
            const int ci = (j < nc) ? cix[j] : -1;
            if (ci >= 0) {
                const bf16x8* kp = (const bf16x8*)(qkvb + (size_t)ci * 3072 + 1024 + hd + d0);
                const bf16x8* vp = (const bf16x8*)(qkvb + (size_t)ci * 3072 + 2048 + hd + d0);
                #pragma unroll
                for (int i = 0; i < 8; i++) {
                    *(bf16x8*)&Ks[j * 136 + d0 + i * 8] = kp[i];
                    *(bf16x8*)&Vs[j * 136 + d0 + i * 8] = vp[i];
                }
            } else {
                #pragma unroll
                for (int i = 0; i < 8; i++) {
                    *(bf16x8*)&Ks[j * 136 + d0 + i * 8] = (bf16x8)(__bf16)0.f;
                    *(bf16x8*)&Vs[j * 136 + d0 + i * 8] = (bf16x8)(__bf16)0.f;
                }
            }
        }
        __syncthreads();
        // S = Q K^T
        {
            f32x4 sacc[2][2];
            #pragma unroll
            for (int i = 0; i < 2; i++)
                #pragma unroll
                for (int j = 0; j < 2; j++) sacc[i][j] = (f32x4){0.f, 0.f, 0.f, 0.f};
            #pragma unroll
            for (int kk = 0; kk < 4; kk++) {
                const int k0 = kk * 32;
                bf16x8 af[2], bk[2];
                af[0] = *(const bf16x8*)&Qs[l15 * 136 + k0 + q4 * 8];
                af[1] = *(const bf16x8*)&Qs[(16 + l15) * 136 + k0 + q4 * 8];
                bk[0] = *(const bf16x8*)&Ks[(nb + l15) * 136 + k0 + q4 * 8];
                bk[1] = *(const bf16x8*)&Ks[(nb + 16 + l15) * 136 + k0 + q4 * 8];
                #pragma unroll
                for (int m2 = 0; m2 < 2; m2++)
                    #pragma unroll
                    for (int n2 = 0; n2 < 2; n2++)
                        sacc[m2][n2] = __builtin_amdgcn_mfma_f32_16x16x32_bf16(af[m2], bk[n2], sacc[m2][n2], 0, 0, 0);
            }
            #pragma unroll
            for (int m2 = 0; m2 < 2; m2++)
                #pragma unroll
                for (int n2 = 0; n2 < 2; n2++)
                    #pragma unroll
                    for (int r = 0; r < 4; r++) {
                        const int row = m2 * 16 + q4 * 4 + r;
                        const int col = nb + n2 * 16 + l15;
                        const int c = cix[col];
                        const int dd = qt0 + row - c;
                        const bool ok = (c >= 0) && (((unsigned)(dd + 32) <= 64u) || cgf[col]);
                        Ss[row * 129 + col] = ok ? sacc[m2][n2][r] * ATT_SCALE : -1e30f;
                    }
        }
        __syncthreads();
        // softmax (normalized) -> Ps bf16
        {
            const int r = t >> 3, i = t & 7;
            float mx = -1e30f;
            for (int c = i; c < 128; c += 8) mx = fmaxf(mx, Ss[r * 129 + c]);
            #pragma unroll
            for (int off = 4; off > 0; off >>= 1) mx = fmaxf(mx, __shfl_down(mx, off, 8));
            mx = __shfl(mx, 0, 8);
            float sm = 0.f;
            for (int c = i; c < 128; c += 8) {
                const float s = Ss[r * 129 + c];
                const float p = (s > -1e29f) ? __expf(s - mx) : 0.f;
                Ss[r * 129 + c] = p;
                sm += p;
            }
            #pragma unroll
            for (int off = 4; off > 0; off >>= 1) sm += __shfl_down(sm, off, 8);
            sm = __shfl(sm, 0, 8);
            const float rl = 1.0f / fmaxf(sm, 1e-30f);
            for (int c = i; c < 128; c += 8) Ps[r * 136 + c] = (__bf16)(Ss[r * 129 + c] * rl);
        }
        __syncthreads();
        // O = P V
        {
            f32x4 oacc[2][2];
            #pragma unroll
            for (int i = 0; i < 2; i++)
                #pragma unroll
                for (int j = 0; j < 2; j++) oacc[i][j] = (f32x4){0.f, 0.f, 0.f, 0.f};
            #pragma unroll
            for (int kk = 0; kk < 4; kk++) {
                const int k0 = kk * 32;
                bf16x8 ap[2], bv[2];
                ap[0] = *(const bf16x8*)&Ps[l15 * 136 + k0 + q4 * 8];
                ap[1] = *(const bf16x8*)&Ps[(16 + l15) * 136 + k0 + q4 * 8];
                #pragma unroll
                for (int n2 = 0; n2 < 2; n2++) {
                    const int dimn = nb + n2 * 16 + l15;
                    #pragma unroll
                    for (int jj = 0; jj < 8; jj++)
                        bv[n2][jj] = Vs[(k0 + q4 * 8 + jj) * 136 + dimn];
                }
                #pragma unroll
                for (int m2 = 0; m2 < 2; m2++)
                    #pragma unroll
                    for (int n2 = 0; n2 < 2; n2++)
                        oacc[m2][n2] = __builtin_amdgcn_mfma_f32_16x16x32_bf16(ap[m2], bv[n2], oacc[m2][n2], 0, 0, 0);
            }
            #pragma unroll
            for (int m2 = 0; m2 < 2; m2++)
                #pragma unroll
                for (int n2 = 0; n2 < 2; n2++)
                    #pragma unroll
                    for (int r = 0; r < 4; r++) {
                        const int row = m2 * 16 + q4 * 4 + r;
                        const int dim = nb + n2 * 16 + l15;
                        const int rt = rtype[row];
                        const size_t o = (size_t)(qt0 + row) * D_MODEL + hd + dim;
                        if (rt == 0)      ctx[o] = (__bf16)oacc[m2][n2][r];
                        else if (rt == 2) ctx[o] = (__bf16)(vmean[hd + dim] * (1.0f / 2048.0f));
                    }
        }
    } else {
        // ================= global partial path (chunk cb) =================
        if (ng == 0) return;
        const int cb = blockIdx.x - 64, c0 = cb * 128;
        {
            const int r = t >> 3, d0 = (t & 7) * 16;
            if (r < ng) {
                const bf16x8* src = (const bf16x8*)(qkvb + (size_t)gcols[r] * 3072 + hd + d0);
                *(bf16x8*)&Qs[r * 136 + d0]     = src[0];
                *(bf16x8*)&Qs[r * 136 + d0 + 8] = src[1];
            } else {
                *(bf16x8*)&Qs[r * 136 + d0]     = (bf16x8)(__bf16)0.f;
                *(bf16x8*)&Qs[r * 136 + d0 + 8] = (bf16x8)(__bf16)0.f;
            }
        }
        if (t < 128) { const int c = c0 + t; cix[t] = (c < T || isg[c]) ? 1 : 0; }  // validity flags
        {
            const int j = t >> 1, d0 = (t & 1) * 64;
            const int ci = c0 + j;
            const bf16x8* kp = (const bf16x8*)(qkvb + (size_t)ci * 3072 + 1024 + hd + d0);
            const bf16x8* vp = (const bf16x8*)(qkvb + (size_t)ci * 3072 + 2048 + hd + d0);
            #pragma unroll
            for (int i = 0; i < 8; i++) {
                *(bf16x8*)&Ks[j * 136 + d0 + i * 8] = kp[i];
                *(bf16x8*)&Vs[j * 136 + d0 + i * 8] = vp[i];
            }
        }
        __syncthreads();
        {
            f32x4 sacc[2][2];
            #pragma unroll
            for (int i = 0; i < 2; i++)
                #pragma unroll
                for (int j = 0; j < 2; j++) sacc[i][j] = (f32x4){0.f, 0.f, 0.f, 0.f};
            #pragma unroll
            for (int kk = 0; kk < 4; kk++) {
                const int k0 = kk * 32;
                bf16x8 af[2], bk[2];
                af[0] = *(const bf16x8*)&Qs[l15 * 136 + k0 + q4 * 8];
                af[1] = *(const bf16x8*)&Qs[(16 + l15) * 136 + k0 + q4 * 8];
                bk[0] = *(const bf16x8*)&Ks[(nb + l15) * 136 + k0 + q4 * 8];
                bk[1] = *(const bf16x8*)&Ks[(nb + 16 + l15) * 136 + k0 + q4 * 8];
                #pragma unroll
                for (int m2 = 0; m2 < 2; m2++)
                    #pragma unroll
                    for (int n2 = 0; n2 < 2; n2++)
                        sacc[m2][n2] = __builtin_amdgcn_mfma_f32_16x16x32_bf16(af[m2], bk[n2], sacc[m2][n2], 0, 0, 0);
            }
            #pragma unroll
            for (int m2 = 0; m2 < 2; m2++)
                #pragma unroll
                for (int n2 = 0; n2 < 2; n2++)
                    #pragma unroll
                    for (int r = 0; r < 4; r++) {
                        const int row = m2 * 16 + q4 * 4 + r;
                        const int col = nb + n2 * 16 + l15;
                        Ss[row * 129 + col] = cix[col] ? sacc[m2][n2][r] * ATT_SCALE : -1e30f;
                    }
        }
        __syncthreads();
        {
            const int r = t >> 3, i = t & 7;
            float mx = -1e30f;
            for (int c = i; c < 128; c += 8) mx = fmaxf(mx, Ss[r * 129 + c]);
            #pragma unroll
            for (int off = 4; off > 0; off >>= 1) mx = fmaxf(mx, __shfl_down(mx, off, 8));
            mx = __shfl(mx, 0, 8);
            float sm = 0.f;
            for (int c = i; c < 128; c += 8) {
                const float s = Ss[r * 129 + c];
                const float p = (s > -1e29f) ? __expf(s - mx) : 0.f;
                Ps[r * 136 + c] = (__bf16)p;
                sm += p;
            }
            #pragma unroll
            for (int off = 4; off > 0; off >>= 1) sm += __shfl_down(sm, off, 8);
            if (i == 0) { mg[(h * 16 + cb) * 32 + r] = mx; lg[(h * 16 + cb) * 32 + r] = sm; }
        }
        __syncthreads();
        {
            f32x4 oacc[2][2];
            #pragma unroll
            for (int i = 0; i < 2; i++)
                #pragma unroll
                for (int j = 0; j < 2; j++) oacc[i][j] = (f32x4){0.f, 0.f, 0.f, 0.f};
            #pragma unroll
            for (int kk = 0; kk < 4; kk++) {
                const int k0 = kk * 32;
                bf16x8 ap[2], bv[2];
                ap[0] = *(const bf16x8*)&Ps[l15 * 136 + k0 + q4 * 8];
                ap[1] = *(const bf16x8*)&Ps[(16 + l15) * 136 + k0 + q4 * 8];
                #pragma unroll
                for (int n2 = 0; n2 < 2; n2++) {
                    const int dimn = nb + n2 * 16 + l15;
                    #pragma unroll
                    for (int jj = 0; jj < 8; jj++)
                        bv[n2][jj] = Vs[(k0 + q4 * 8 + jj) * 136 + dimn];
                }
                #pragma unroll
                for (int m2 = 0; m2 < 2; m2++)
                    #pragma unroll
                    for (int n2 = 0; n2 < 2; n2++)
                        oacc[m2][n2] = __builtin_amdgcn_mfma_f32_16x16x32_bf16(ap[m2], bv[n2], oacc[m2][n2], 0, 0, 0);
            }
            #pragma unroll
            for (int m2 = 0; m2 < 2; m2++)
                #pragma unroll
                for (int n2 = 0; n2 < 2; n2++)
                    #pragma unroll
                    for (int r = 0; r < 4; r++) {
                        const int row = m2 * 16 + q4 * 4 + r;
                        const int dim = nb + n2 * 16 + l15;
                        Og[((size_t)(h * 16 + cb) * 32 + row) * 128 + dim] = oacc[m2][n2][r];
                    }
        }
    }
}

// combine the 16 chunks for global rows
__global__ __launch_bounds__(256)
void attn_gcomb(const int* __restrict__ gcols, const int* __restrict__ ngcp,
                const float* __restrict__ Og, const float* __restrict__ mg,
                const float* __restrict__ lg, __bf16* __restrict__ ctx) {
    const int h = blockIdx.x, hd = h * 128, t = threadIdx.x;
    const int ng = *ngcp;
    const int r = t >> 3, i = t & 7;
    if (r >= ng) return;
    float M = -1e30f;
    #pragma unroll
    for (int cb = 0; cb < 16; cb++) M = fmaxf(M, mg[(h * 16 + cb) * 32 + r]);
    float e[16], L = 0.f;
    #pragma unroll
    for (int cb = 0; cb < 16; cb++) {
        e[cb] = __expf(mg[(h * 16 + cb) * 32 + r] - M);
        L += e[cb] * lg[(h * 16 + cb) * 32 + r];
    }
    const float rL = 1.0f / fmaxf(L, 1e-30f);
    const int grow = gcols[r];
    for (int d = i; d < 128; d += 8) {
        float o = 0.f;
        #pragma unroll
        for (int cb = 0; cb < 16; cb++)
            o += e[cb] * Og[((size_t)(h * 16 + cb) * 32 + r) * 128 + d];
        ctx[(size_t)grow * D_MODEL + hd + d] = (__bf16)(o * rL);
    }
}

// x = LN(y + r); writes fp32 (xo) + bf16 (xb). vz: optional vmean zeroing (block 0).
__global__ __launch_bounds__(256)
void ln_kernel(const float* __restrict__ y, const float* __restrict__ r,
               const float* __restrict__ g, const float* __restrict__ b,
               float* __restrict__ xo, __bf16* __restrict__ xb, float* __restrict__ vz) {
    const int row = blockIdx.x, t = threadIdx.x;
    if (vz != nullptr && row == 0) {
        #pragma unroll
        for (int i = 0; i < 4; i++) vz[t + i * 256] = 0.0f;
    }
    const float* yr = y + (size_t)row * D_MODEL;
    const float* rr = r + (size_t)row * D_MODEL;
    __shared__ float red[4];
    float v[4]; float s = 0.f;
    #pragma unroll
    for (int i = 0; i < 4; i++) { const int d = t + i * 256; v[i] = yr[d] + rr[d]; s += v[i]; }
    s = blockRedSum<4>(s, red);
    const float mu = s * (1.0f / 1024.0f);
    float vs = 0.f;
    #pragma unroll
    for (int i = 0; i < 4; i++) { const float dd = v[i] - mu; vs += dd * dd; }
    vs = blockRedSum<4>(vs, red);
    const float rstd = rsqrtf(vs * (1.0f / 1024.0f) + 1e-5f);
    #pragma unroll
    for (int i = 0; i < 4; i++) {
        const int d = t + i * 256;
        const float o = g[d] * (v[i] - mu) * rstd + b[d];
        xo[(size_t)row * D_MODEL + d] = o;
        xb[(size_t)row * D_MODEL + d] = (__bf16)o;
    }
}

extern "C" void kernel_launch(void* const* d_in, const int* in_sizes, int n_in,
                              void* d_out, int out_size, void* d_ws, size_t ws_size,
                              hipStream_t stream) {
    const int*   Tp   = (const int*)  d_in[0];
    const float* enc  = (const float*)d_in[1];
    const int*   gidx = (const int*)  d_in[2];
    const float* Wq   = (const float*)d_in[3];
    const float* Wk   = (const float*)d_in[4];
    const float* Wv   = (const float*)d_in[5];
    const float* Wo   = (const float*)d_in[6];
    const float* ln1g = (const float*)d_in[7];
    const float* ln1b = (const float*)d_in[8];
    const float* W1   = (const float*)d_in[9];
    const float* W2   = (const float*)d_in[10];
    const float* ln2g = (const float*)d_in[11];
    const float* ln2b = (const float*)d_in[12];

    char* p = (char*)d_ws;
    size_t off = 0;
    auto alloc = [&](size_t bytes) -> void* {
        void* q = p + off;
        off += (bytes + 255) & ~(size_t)255;
        return q;
    };
    float*  x     = (float*) alloc((size_t)S_LEN * D_MODEL * 4);
    __bf16* xb    = (__bf16*)alloc((size_t)S_LEN * D_MODEL * 2);
    __bf16* qkvb  = (__bf16*)alloc((size_t)S_LEN * 3072 * 2);
    __bf16* ctx   = (__bf16*)alloc((size_t)S_LEN * D_MODEL * 2);
    float*  g1    = (float*) alloc((size_t)S_LEN * D_MODEL * 4);
    __bf16* h1    = (__bf16*)alloc((size_t)S_LEN * D_FF * 2);
    __bf16* wT    = (__bf16*)alloc((size_t)4 * 8 * 1024 * 1024 * 2);   // 4-layer arena (64 MB)
    float*  vmean = (float*) alloc(1024 * 4);
    int*    isg   = (int*)   alloc(S_LEN * 4);
    int*    gcols = (int*)   alloc(S_LEN * 4);
    int*    ngc   = (int*)   alloc(256);
    float*  Og    = (float*) alloc((size_t)8 * 16 * 32 * 128 * 4);
    float*  mgb   = (float*) alloc(8 * 16 * 32 * 4);
    float*  lgb   = (float*) alloc(8 * 16 * 32 * 4);

    init_mask_kernel<<<S_LEN + 1, 256, 0, stream>>>(enc, x, xb, gidx, isg, gcols, ngc, vmean);
    transpose_all_kernel<<<2048, 256, 0, stream>>>(Wq, Wk, Wv, Wo, W1, W2, wT);

    for (int l = 0; l < NLAYER; l++) {
        __bf16* wL = wT + (size_t)l * 8 * 1024 * 1024;
        // --- QKV projection (fused N=3072, bf16 out + fused vmean), BK=64 ---
        gemm_bt<64, 128, 2, true><<<dim3(24, 32), 256, 0, stream>>>(xb, wL, (void*)qkvb, vmean, S_LEN, 3072, 1024);

        // --- attention: local tiles + global partials in one dispatch ---
        attn_kernel<<<dim3(80, 8), 256, 0, stream>>>(qkvb, Tp, isg, gcols, ngc, vmean, ctx, Og, mgb, lgb);
        attn_gcomb<<<8, 256, 0, stream>>>(gcols, ngc, Og, mgb, lgb, ctx);

        // --- output projection + LN1 ---
        gemm_bt<64, 64, 0, false><<<dim3(16, 32), 256, 0, stream>>>(ctx, wL + (size_t)3 * 1024 * 1024, (void*)g1, nullptr, S_LEN, 1024, 1024);
        ln_kernel<<<S_LEN, 256, 0, stream>>>(g1, x, ln1g + l * 1024, ln1b + l * 1024, x, xb, nullptr);

        // --- FFN ---
        gemm_bt<64, 64, 1, false><<<dim3(32, 32), 256, 0, stream>>>(xb, wL + (size_t)4 * 1024 * 1024, (void*)h1, nullptr, S_LEN, 2048, 1024);
        gemm_bt<64, 64, 0, false><<<dim3(16, 32), 256, 0, stream>>>(h1, wL + (size_t)6 * 1024 * 1024, (void*)g1, nullptr, S_LEN, 1024, 2048);
        float* xout = (l == NLAYER - 1) ? (float*)d_out : x;
        ln_kernel<<<S_LEN, 256, 0, stream>>>(g1, x, ln2g + l * 1024, ln2b + l * 1024, xout, xb, vmean);
    }
}